// Round 2
// baseline (1111.652 us; speedup 1.0000x reference)
//
#include <hip/hip_runtime.h>
#include <stdint.h>

typedef float     f32x4 __attribute__((ext_vector_type(4)));
typedef _Float16  f16x8 __attribute__((ext_vector_type(8)));
typedef uint32_t  u32x4 __attribute__((ext_vector_type(4)));

#define MTOT 131072
#define NC   512
#define BM   256
#define BN   256
#define BK   32
#define KSTEPS (NC / BK)          // 16
#define LDS_BUF 65536             // per double-buffer half
// per buffer: A fp32 [256][32] = 32768 B; Bhi f16 [256][32] = 16384; Blo = 16384

__device__ __forceinline__ void gload_lds16(const void* g, void* l) {
    using GP = const __attribute__((address_space(1))) uint32_t*;
    using LP = __attribute__((address_space(3))) uint32_t*;
    __builtin_amdgcn_global_load_lds((GP)g, (LP)l, 16, 0, 0);
}

// ---- prepass 1: W[k][n] -> Wt_hi[n][k], Wt_lo[n][k] (f16 split, transposed) ----
__global__ void prep_w(const float* __restrict__ W,
                       _Float16* __restrict__ wh, _Float16* __restrict__ wl) {
    __shared__ float tile[32][33];
    int b  = blockIdx.x;
    int bk = (b & 15) << 5;       // k-tile base (rows of W)
    int bn = (b >> 4) << 5;       // n-tile base (cols of W)
    int tx = threadIdx.x & 31;
    int ty = threadIdx.x >> 5;    // 0..7
#pragma unroll
    for (int i = 0; i < 4; ++i) {
        int r = ty + i * 8;
        tile[r][tx] = W[(size_t)(bk + r) * NC + bn + tx];
    }
    __syncthreads();
#pragma unroll
    for (int i = 0; i < 4; ++i) {
        int r = ty + i * 8;                  // output row within n-tile
        float v = tile[tx][r];               // = W[bk+tx][bn+r]
        _Float16 h = (_Float16)v;
        size_t o = (size_t)(bn + r) * NC + bk + tx;
        wh[o] = h;
        wl[o] = (_Float16)(v - (float)h);
    }
}

// ---- prepass 2: bias[n] = sum_k rm[k] * W[k][n] (fp32) ----
__global__ void prep_bias(const float* __restrict__ W, const float* __restrict__ rm,
                          float* __restrict__ bias) {
    int n = blockIdx.x * 256 + threadIdx.x;
    float s = 0.f;
    for (int k = 0; k < NC; ++k) s += rm[k] * W[(size_t)k * NC + n];
    bias[n] = s;
}

// ---- main GEMM: out = X @ W - bias, f16 hi/lo split, MFMA 16x16x32 ----
__global__ __launch_bounds__(512, 2)
void gemm_split_f16(const float* __restrict__ X,
                    const _Float16* __restrict__ Wh,
                    const _Float16* __restrict__ Wl,
                    const float* __restrict__ bias,
                    float* __restrict__ out) {
    extern __shared__ __align__(16) char smem[];

    // XCD-aware swizzle: 1024 blocks, 8 XCDs, 1024%8==0 -> contiguous band per XCD;
    // adjacent swz pairs share the same X row-tile -> second read is an L2 hit.
    int bid = blockIdx.x;
    int swz = (bid & 7) * (1024 / 8) + (bid >> 3);
    const int r0 = (swz >> 1) * BM;   // row-tile
    const int n0 = (swz & 1) * BN;    // col-tile

    const int t    = threadIdx.x;
    const int lane = t & 63;
    const int w    = t >> 6;
    const int wr   = w >> 2;          // 0..1  (wave row)
    const int wc   = w & 3;           // 0..3  (wave col)
    const int l15  = lane & 15;
    const int lg   = lane >> 4;       // 0..3

    f32x4 acc[8][4];
#pragma unroll
    for (int m = 0; m < 8; ++m)
#pragma unroll
        for (int n = 0; n < 4; ++n) acc[m][n] = (f32x4){0.f, 0.f, 0.f, 0.f};

    // stage K-step kt into buffer buf (linear LDS dest; swizzle folded into global src)
    auto stage = [&](int kt, int buf) {
        const int k0 = kt * BK;
        char* aB  = smem + buf * LDS_BUF;
        char* bHi = aB + 32768;
        char* bLo = aB + 49152;
#pragma unroll
        for (int i = 0; i < 4; ++i) {          // A: 2048 slots of 16B, fp32 [256][32]
            int s   = t + i * 512;
            int row = s >> 3;
            int cs  = (s & 7) ^ (row & 7);     // XOR-swizzle (bank-spread on frag reads)
            gload_lds16(X + ((size_t)(r0 + row) * NC + k0 + cs * 4), aB + s * 16);
        }
#pragma unroll
        for (int i = 0; i < 2; ++i) {          // B hi/lo: 1024 slots of 16B each, f16 [256][32]
            int s   = t + i * 512;
            int row = s >> 2;
            int cs  = (s & 3) ^ ((row >> 1) & 3);
            size_t go = (size_t)(n0 + row) * NC + k0 + cs * 8;
            gload_lds16(Wh + go, bHi + s * 16);
            gload_lds16(Wl + go, bLo + s * 16);
        }
    };

    stage(0, 0);
    asm volatile("s_waitcnt vmcnt(0)" ::: "memory");
    __builtin_amdgcn_s_barrier();

    int cur = 0;
    for (int kt = 0; kt < KSTEPS; ++kt) {
        if (kt < KSTEPS - 1) stage(kt + 1, cur ^ 1);   // prefetch overlaps MFMA below

        const char* aB  = smem + cur * LDS_BUF;
        const char* bHi = aB + 32768;
        const char* bLo = aB + 49152;

        // B fragments: bh[nf][j] = Wt[n0+row][k0 + 8*lg + j]
        f16x8 bh[4], bl[4];
        int anyLo = 0;
#pragma unroll
        for (int nf = 0; nf < 4; ++nf) {
            int row = wc * 64 + nf * 16 + l15;
            int c   = lg ^ ((row >> 1) & 3);
            bh[nf] = *(const f16x8*)(bHi + row * 64 + c * 16);
            bl[nf] = *(const f16x8*)(bLo + row * 64 + c * 16);
            u32x4 uv = __builtin_bit_cast(u32x4, bl[nf]);
            anyLo |= (uv.x | uv.y | uv.z | uv.w);
        }
        const bool useLo = __any(anyLo != 0) != 0;     // wave-uniform; W==I -> all lo==0

#define MF_BODY(DO_LO)                                                              \
        _Pragma("unroll")                                                           \
        for (int mf = 0; mf < 8; ++mf) {                                            \
            int row = wr * 128 + mf * 16 + l15;                                     \
            int c0  = (2 * lg)     ^ (row & 7);                                     \
            int c1  = (2 * lg + 1) ^ (row & 7);                                     \
            f32x4 x0 = *(const f32x4*)(aB + row * 128 + c0 * 16);                   \
            f32x4 x1 = *(const f32x4*)(aB + row * 128 + c1 * 16);                   \
            f16x8 ah, al;                                                           \
            _Pragma("unroll")                                                       \
            for (int i = 0; i < 4; ++i) {                                           \
                _Float16 h0 = (_Float16)x0[i];                                      \
                ah[i] = h0; al[i] = (_Float16)(x0[i] - (float)h0);                  \
                _Float16 h1 = (_Float16)x1[i];                                      \
                ah[i + 4] = h1; al[i + 4] = (_Float16)(x1[i] - (float)h1);          \
            }                                                                       \
            _Pragma("unroll")                                                       \
            for (int nf = 0; nf < 4; ++nf) {                                        \
                acc[mf][nf] = __builtin_amdgcn_mfma_f32_16x16x32_f16(ah, bh[nf], acc[mf][nf], 0, 0, 0); \
                acc[mf][nf] = __builtin_amdgcn_mfma_f32_16x16x32_f16(al, bh[nf], acc[mf][nf], 0, 0, 0); \
                if (DO_LO)                                                          \
                    acc[mf][nf] = __builtin_amdgcn_mfma_f32_16x16x32_f16(ah, bl[nf], acc[mf][nf], 0, 0, 0); \
            }                                                                       \
        }

        if (useLo) { MF_BODY(true) } else { MF_BODY(false) }
#undef MF_BODY

        if (kt < KSTEPS - 1) {
            asm volatile("s_waitcnt vmcnt(0)" ::: "memory");  // drain prefetch before buffer swap
            __builtin_amdgcn_s_barrier();
            cur ^= 1;
        }
    }

    // epilogue: C/D layout col=lane&15, row=(lane>>4)*4+reg
    float bv[4];
#pragma unroll
    for (int nf = 0; nf < 4; ++nf) bv[nf] = bias[n0 + wc * 64 + nf * 16 + l15];
#pragma unroll
    for (int mf = 0; mf < 8; ++mf) {
        int grBase = r0 + wr * 128 + mf * 16 + lg * 4;
#pragma unroll
        for (int nf = 0; nf < 4; ++nf) {
            int gc = n0 + wc * 64 + nf * 16 + l15;
#pragma unroll
            for (int j = 0; j < 4; ++j)
                out[(size_t)(grBase + j) * NC + gc] = acc[mf][nf][j] - bv[nf];
        }
    }
}

extern "C" void kernel_launch(void* const* d_in, const int* in_sizes, int n_in,
                              void* d_out, int out_size, void* d_ws, size_t ws_size,
                              hipStream_t stream) {
    (void)in_sizes; (void)n_in; (void)out_size; (void)ws_size;
    const float* X  = (const float*)d_in[0];
    const float* rm = (const float*)d_in[1];
    const float* rW = (const float*)d_in[2];
    float* out = (float*)d_out;

    _Float16* wh = (_Float16*)d_ws;                       // 512 KB
    _Float16* wl = wh + (size_t)NC * NC;                  // 512 KB
    float* bias  = (float*)(wl + (size_t)NC * NC);        // 2 KB

    prep_w<<<256, 256, 0, stream>>>(rW, wh, wl);
    prep_bias<<<2, 256, 0, stream>>>(rW, rm, bias);

    hipFuncSetAttribute(reinterpret_cast<const void*>(gemm_split_f16),
                        hipFuncAttributeMaxDynamicSharedMemorySize, 2 * LDS_BUF);
    gemm_split_f16<<<(MTOT / BM) * (NC / BN), 512, 2 * LDS_BUF, stream>>>(X, wh, wl, bias, out);
}

// Round 3
// 934.857 us; speedup vs baseline: 1.1891x; 1.1891x over previous
//
#include <hip/hip_runtime.h>
#include <stdint.h>

typedef float     f32x4 __attribute__((ext_vector_type(4)));
typedef _Float16  f16x8 __attribute__((ext_vector_type(8)));
typedef uint32_t  u32x4 __attribute__((ext_vector_type(4)));

#define MTOT 131072
#define NC   512
#define BM   128          // block covers 128 rows x FULL 512 cols -> X read exactly once
#define BK   32
#define KSTEPS (NC / BK)  // 16
#define ABUF  16384       // A fp32 [128][32] bytes per staging buffer
#define EPAD  68          // epilogue LDS row stride in f32 ([16][68], bank-safe, 16B-aligned)
#define EPW   (16 * EPAD * 4)      // 4352 B per-wave epilogue region
#define LDS_TOTAL (8 * EPW)        // 34816 B >= 2*ABUF (staging aliases epilogue)

__device__ __forceinline__ void gload_lds16(const void* g, void* l) {
    using GP = const __attribute__((address_space(1))) uint32_t*;
    using LP = __attribute__((address_space(3))) uint32_t*;
    __builtin_amdgcn_global_load_lds((GP)g, (LP)l, 16, 0, 0);
}

// ---- prepass 1: W[k][n] -> hi/lo f16 split in MFMA-tiled layout ----
// element (n,k) stored at ((n>>4)*64 + (k>>3))*128 + (n&15)*8 + (k&7)
// so a wave's B-fragment load (16 n-rows x 8 k) is 16B/lane, 1KB contiguous/instr.
__global__ void prep_w(const float* __restrict__ W,
                       _Float16* __restrict__ wh, _Float16* __restrict__ wl) {
    __shared__ float tile[32][33];
    int b  = blockIdx.x;
    int bk = (b & 15) << 5;       // k-tile base (rows of W)
    int bn = (b >> 4) << 5;       // n-tile base (cols of W)
    int tx = threadIdx.x & 31;
    int ty = threadIdx.x >> 5;    // 0..7
#pragma unroll
    for (int i = 0; i < 4; ++i) {
        int r = ty + i * 8;
        tile[r][tx] = W[(size_t)(bk + r) * NC + bn + tx];
    }
    __syncthreads();
#pragma unroll
    for (int i = 0; i < 4; ++i) {
        int r = ty + i * 8;
        int n = bn + r, k = bk + tx;
        float v = tile[tx][r];               // = W[k][n]
        _Float16 h = (_Float16)v;
        size_t o = (size_t)(((n >> 4) * 64 + (k >> 3)) * 128 + (n & 15) * 8 + (k & 7));
        wh[o] = h;
        wl[o] = (_Float16)(v - (float)h);
    }
}

// ---- prepass 2: bias[n] = sum_k rm[k] * W[k][n] (fp32) ----
__global__ void prep_bias(const float* __restrict__ W, const float* __restrict__ rm,
                          float* __restrict__ bias) {
    int n = blockIdx.x * 256 + threadIdx.x;
    float s = 0.f;
    for (int k = 0; k < NC; ++k) s += rm[k] * W[(size_t)k * NC + n];
    bias[n] = s;
}

// ---- main GEMM: out = X @ W - bias;  f16 hi/lo split, MFMA 16x16x32 ----
// 8 waves in a 1x8 col grid: wave tile 128x64. A staged in LDS (dbuf),
// B read per-kt straight from L2-resident tiled arrays into registers.
__global__ __launch_bounds__(512, 2)
void gemm_xw(const float* __restrict__ X,
             const _Float16* __restrict__ Wh,
             const _Float16* __restrict__ Wl,
             const float* __restrict__ bias,
             float* __restrict__ out) {
    extern __shared__ __align__(16) char smem[];

    const int r0   = blockIdx.x * BM;
    const int t    = threadIdx.x;
    const int lane = t & 63;
    const int w    = t >> 6;          // 0..7
    const int cb   = w * 64;          // wave's output-col base
    const int l15  = lane & 15;
    const int lg   = lane >> 4;       // 0..3

    f32x4 acc[8][4];
#pragma unroll
    for (int m = 0; m < 8; ++m)
#pragma unroll
        for (int n = 0; n < 4; ++n) acc[m][n] = (f32x4){0.f, 0.f, 0.f, 0.f};

    // A-fragment lane byte-offsets within a staging buffer (XOR-swizzled).
    // row = mf*16 + l15 -> sw = l15&7 (mf*16 = 0 mod 8); chunks 2lg, 2lg+1.
    const int swA   = l15 & 7;
    const int aoff0 = l15 * 128 + ((2 * lg) ^ swA) * 16;
    const int aoff1 = l15 * 128 + ((2 * lg + 1) ^ swA) * 16;

    // B lane byte-offset constants (tiled layout)
    const int bLane = (w * 4) * 16384 + lg * 256 + l15 * 16;

    // stage K-step kt into buffer buf: 1024 slots of 16B, 2 per thread
    auto stage = [&](int kt, int buf) {
        char* aB = smem + buf * ABUF;
#pragma unroll
        for (int i = 0; i < 2; ++i) {
            int s   = t + i * 512;
            int row = s >> 3;
            int cs  = (s & 7) ^ (row & 7);     // swizzle folded into global src
            gload_lds16(X + ((size_t)(r0 + row) * NC + kt * BK + cs * 4), aB + s * 16);
        }
    };

    stage(0, 0);
    asm volatile("s_waitcnt vmcnt(0)" ::: "memory");
    __builtin_amdgcn_s_barrier();

    int cur = 0;
    for (int kt = 0; kt < KSTEPS; ++kt) {
        if (kt < KSTEPS - 1) stage(kt + 1, cur ^ 1);   // prefetch overlaps MFMA

        const char* aB = smem + cur * ABUF;

        // B fragments straight from global (L2-resident, fully coalesced 1KB/instr)
        f16x8 bh[4], bl[4];
        int anyLo = 0;
#pragma unroll
        for (int nf = 0; nf < 4; ++nf) {
            int off = bLane + nf * 16384 + kt * 1024;
            bh[nf] = *(const f16x8*)((const char*)Wh + off);
            bl[nf] = *(const f16x8*)((const char*)Wl + off);
            u32x4 uv = __builtin_bit_cast(u32x4, bl[nf]);
            anyLo |= (uv.x | uv.y | uv.z | uv.w);
        }
        const bool useLo = __any(anyLo != 0) != 0;   // wave-uniform; W==I -> skip lo

#define MF_BODY(DO_LO)                                                              \
        _Pragma("unroll")                                                           \
        for (int mf = 0; mf < 8; ++mf) {                                            \
            f32x4 x0 = *(const f32x4*)(aB + mf * 2048 + aoff0);                     \
            f32x4 x1 = *(const f32x4*)(aB + mf * 2048 + aoff1);                     \
            f16x8 ah, al;                                                           \
            _Pragma("unroll")                                                       \
            for (int i = 0; i < 4; ++i) {                                           \
                _Float16 h0 = (_Float16)x0[i];                                      \
                ah[i] = h0; al[i] = (_Float16)(x0[i] - (float)h0);                  \
                _Float16 h1 = (_Float16)x1[i];                                      \
                ah[i + 4] = h1; al[i + 4] = (_Float16)(x1[i] - (float)h1);          \
            }                                                                       \
            _Pragma("unroll")                                                       \
            for (int nf = 0; nf < 4; ++nf) {                                        \
                acc[mf][nf] = __builtin_amdgcn_mfma_f32_16x16x32_f16(ah, bh[nf], acc[mf][nf], 0, 0, 0); \
                acc[mf][nf] = __builtin_amdgcn_mfma_f32_16x16x32_f16(al, bh[nf], acc[mf][nf], 0, 0, 0); \
                if (DO_LO)                                                          \
                    acc[mf][nf] = __builtin_amdgcn_mfma_f32_16x16x32_f16(ah, bl[nf], acc[mf][nf], 0, 0, 0); \
            }                                                                       \
        }

        if (useLo) { MF_BODY(true) } else { MF_BODY(false) }
#undef MF_BODY

        if (kt < KSTEPS - 1) {
            asm volatile("s_waitcnt vmcnt(0)" ::: "memory");  // staged data landed
            __builtin_amdgcn_s_barrier();
            cur ^= 1;
        }
    }

    // ---- epilogue: per-wave LDS transpose -> contiguous dwordx4 stores ----
    __syncthreads();                       // staging reads done; safe to reuse LDS
    float bv[4];
#pragma unroll
    for (int nf = 0; nf < 4; ++nf) bv[nf] = bias[cb + nf * 16 + l15];

    char* eB = smem + w * EPW;             // private [16][EPAD] f32 region
#pragma unroll
    for (int mf = 0; mf < 8; ++mf) {
        // scatter fragment (C/D layout: col=l15, row=lg*4+j) into LDS
#pragma unroll
        for (int nf = 0; nf < 4; ++nf)
#pragma unroll
            for (int j = 0; j < 4; ++j) {
                int r16 = lg * 4 + j;
                int col = nf * 16 + l15;
                *(float*)(eB + (r16 * EPAD + col) * 4) = acc[mf][nf][j] - bv[nf];
            }
        // gather rows lane-contiguous: 4 rows x 256B fully-dense per instr
#pragma unroll
        for (int ri = 0; ri < 4; ++ri) {
            int r16 = ri * 4 + lg;
            f32x4 v = *(const f32x4*)(eB + (r16 * EPAD + l15 * 4) * 4);
            int grow = r0 + mf * 16 + r16;
            *(f32x4*)(out + (size_t)grow * NC + cb + l15 * 4) = v;
        }
    }
}

extern "C" void kernel_launch(void* const* d_in, const int* in_sizes, int n_in,
                              void* d_out, int out_size, void* d_ws, size_t ws_size,
                              hipStream_t stream) {
    (void)in_sizes; (void)n_in; (void)out_size; (void)ws_size;
    const float* X  = (const float*)d_in[0];
    const float* rm = (const float*)d_in[1];
    const float* rW = (const float*)d_in[2];
    float* out = (float*)d_out;

    _Float16* wh = (_Float16*)d_ws;                       // 512 KB
    _Float16* wl = wh + (size_t)NC * NC;                  // 512 KB
    float* bias  = (float*)(wl + (size_t)NC * NC);        // 2 KB

    prep_w<<<256, 256, 0, stream>>>(rW, wh, wl);
    prep_bias<<<2, 256, 0, stream>>>(rW, rm, bias);

    gemm_xw<<<MTOT / BM, 512, LDS_TOTAL, stream>>>(X, wh, wl, bias, out);
}